// Round 1
// baseline (19024.625 us; speedup 1.0000x reference)
//
#include <hip/hip_runtime.h>
#include <cstddef>
#include <cstdint>

constexpr int kSeq = 512;
constexpr int kH   = 256;   // hidden per direction
constexpr int kG   = 1024;  // 4*kH (gates)
constexpr int kE   = 320;   // embed dim
constexpr int kLH  = 512;   // 2*kH
constexpr int kMLP = 512;

__device__ __forceinline__ float fexp2f(float x) {
  float r; asm("v_exp_f32 %0, %1" : "=v"(r) : "v"(x)); return r;
}
__device__ __forceinline__ float frcpf(float x) {
  float r; asm("v_rcp_f32 %0, %1" : "=v"(r) : "v"(x)); return r;
}
__device__ __forceinline__ float sigm(float x) {
  return frcpf(1.0f + fexp2f(-1.4426950408889634f * x));
}
__device__ __forceinline__ float tanh_(float x) {
  // tanh(x) = 1 - 2/(1+e^{2x}); e^{2x} = 2^(x*2*log2(e)). inf-safe at both ends.
  return 1.0f - 2.0f * frcpf(1.0f + fexp2f(2.8853900817779268f * x));
}

// ---------------- embedding gather ----------------
__global__ void embed_k(const int* __restrict__ wt, const int* __restrict__ pt,
                        const float* __restrict__ we, const float* __restrict__ pe,
                        float* __restrict__ X) {
  const int t = blockIdx.x;
  const int c = threadIdx.x;  // 0..319
  const int w = wt[t];
  const int p = pt[t];
  X[t * kE + c] = (c < 256) ? we[(size_t)w * 256 + c] : pe[p * 64 + (c - 256)];
}

// ---------------- generic f32 "NT" GEMM ----------------
// C[m,n] = scale * (sum_k A[m,k]*B[n,k] + b1[n] + b2[n])
// C addressed as C[m*csm + n*csn] so outputs can be stored transposed.
template <int BM, int BN, int BK>
__global__ __launch_bounds__(256) void gemm_nt(
    const float* __restrict__ A, int lda,
    const float* __restrict__ B, int ldb,
    const float* __restrict__ b1, const float* __restrict__ b2, float scale,
    float* __restrict__ C, int csm, int csn, int K) {
  const int tid = threadIdx.x;
  const int m0 = blockIdx.y * BM;
  const int n0 = blockIdx.x * BN;
  __shared__ float As[BK][BM];
  __shared__ float Bs[BK][BN];
  const int lm = tid >> 2;   // 0..63
  const int lk = tid & 3;    // k-quad
  const int tx = tid & 15;
  const int ty = tid >> 4;
  float acc[4][4] = {};
  for (int k0 = 0; k0 < K; k0 += BK) {
    const float4 av = *(const float4*)(A + (size_t)(m0 + lm) * lda + k0 + lk * 4);
    const float4 bv = *(const float4*)(B + (size_t)(n0 + lm) * ldb + k0 + lk * 4);
    __syncthreads();
    As[lk * 4 + 0][lm] = av.x; As[lk * 4 + 1][lm] = av.y;
    As[lk * 4 + 2][lm] = av.z; As[lk * 4 + 3][lm] = av.w;
    Bs[lk * 4 + 0][lm] = bv.x; Bs[lk * 4 + 1][lm] = bv.y;
    Bs[lk * 4 + 2][lm] = bv.z; Bs[lk * 4 + 3][lm] = bv.w;
    __syncthreads();
#pragma unroll
    for (int kk = 0; kk < BK; ++kk) {
      const float4 a = *(const float4*)&As[kk][ty * 4];
      const float4 b = *(const float4*)&Bs[kk][tx * 4];
      acc[0][0] = fmaf(a.x, b.x, acc[0][0]);
      acc[0][1] = fmaf(a.x, b.y, acc[0][1]);
      acc[0][2] = fmaf(a.x, b.z, acc[0][2]);
      acc[0][3] = fmaf(a.x, b.w, acc[0][3]);
      acc[1][0] = fmaf(a.y, b.x, acc[1][0]);
      acc[1][1] = fmaf(a.y, b.y, acc[1][1]);
      acc[1][2] = fmaf(a.y, b.z, acc[1][2]);
      acc[1][3] = fmaf(a.y, b.w, acc[1][3]);
      acc[2][0] = fmaf(a.z, b.x, acc[2][0]);
      acc[2][1] = fmaf(a.z, b.y, acc[2][1]);
      acc[2][2] = fmaf(a.z, b.z, acc[2][2]);
      acc[2][3] = fmaf(a.z, b.w, acc[2][3]);
      acc[3][0] = fmaf(a.w, b.x, acc[3][0]);
      acc[3][1] = fmaf(a.w, b.y, acc[3][1]);
      acc[3][2] = fmaf(a.w, b.z, acc[3][2]);
      acc[3][3] = fmaf(a.w, b.w, acc[3][3]);
    }
  }
#pragma unroll
  for (int ii = 0; ii < 4; ++ii) {
#pragma unroll
    for (int jj = 0; jj < 4; ++jj) {
      const int m = m0 + ty * 4 + ii;
      const int n = n0 + tx * 4 + jj;
      float v = acc[ii][jj];
      if (b1) v += b1[n];
      if (b2) v += b2[n];
      C[(size_t)m * csm + (size_t)n * csn] = v * scale;
    }
  }
}

// ---------------- sequential LSTM scan, one block per direction ----------------
// pre: (2, kSeq, kG) pregates = x@Wih.T + bih + bhh (precomputed)
// whh: (2, kG, kH)   out: (kSeq, 2*kH), dir d writes columns [d*kH, d*kH+kH)
// 1024 threads. Thread t: k-half kh = t>>9, output pair j0=2*(t&511), j0+1.
// Whh held entirely in VGPRs (256 f32/thread). h broadcast via LDS.
__global__ __launch_bounds__(1024, 1) void lstm_scan(
    const float* __restrict__ pre, const float* __restrict__ whh,
    float* __restrict__ out) {
  const int d  = blockIdx.x;
  const int t  = threadIdx.x;
  const int kh = t >> 9;
  const int jj = t & 511;
  const int j0 = jj * 2;
  float w0[128], w1[128];
  {
    const float* r0 = whh + ((size_t)d * kG + j0) * kH + kh * 128;
    const float* r1 = r0 + kH;
#pragma unroll
    for (int k = 0; k < 128; k += 4) {
      const float4 a = *(const float4*)(r0 + k);
      const float4 b = *(const float4*)(r1 + k);
      w0[k] = a.x; w0[k + 1] = a.y; w0[k + 2] = a.z; w0[k + 3] = a.w;
      w1[k] = b.x; w1[k + 1] = b.y; w1[k + 2] = b.z; w1[k + 3] = b.w;
    }
  }
  __shared__ __align__(16) float h_sh[kH];
  __shared__ __align__(8) float pg[2][kG];
  float c = 0.0f;
  if (t < kH) h_sh[t] = 0.0f;
  __syncthreads();
  for (int s = 0; s < kSeq; ++s) {
    const int ts = d ? (kSeq - 1 - s) : s;
    // issue pregate loads early; latency hides under the dot below
    float p0 = 0.f, p1 = 0.f, p2 = 0.f, p3 = 0.f;
    if (t < kH) {
      const float* p = pre + ((size_t)d * kSeq + ts) * kG;
      p0 = p[t]; p1 = p[kH + t]; p2 = p[2 * kH + t]; p3 = p[3 * kH + t];
    }
    const float* hp = h_sh + kh * 128;
    float a0 = 0.0f, a1 = 0.0f;
#pragma unroll
    for (int k = 0; k < 128; k += 4) {
      const float4 hv = *(const float4*)(hp + k);
      a0 = fmaf(w0[k], hv.x, a0);
      a0 = fmaf(w0[k + 1], hv.y, a0);
      a0 = fmaf(w0[k + 2], hv.z, a0);
      a0 = fmaf(w0[k + 3], hv.w, a0);
      a1 = fmaf(w1[k], hv.x, a1);
      a1 = fmaf(w1[k + 1], hv.y, a1);
      a1 = fmaf(w1[k + 2], hv.z, a1);
      a1 = fmaf(w1[k + 3], hv.w, a1);
    }
    *(float2*)&pg[kh][j0] = make_float2(a0, a1);
    __syncthreads();
    if (t < kH) {
      const float gi = pg[0][t]          + pg[1][t]          + p0;
      const float gf = pg[0][kH + t]     + pg[1][kH + t]     + p1;
      const float gg = pg[0][2 * kH + t] + pg[1][2 * kH + t] + p2;
      const float go = pg[0][3 * kH + t] + pg[1][3 * kH + t] + p3;
      const float iv = sigm(gi), fv = sigm(gf);
      const float gv = tanh_(gg), ov = sigm(go);
      c = fv * c + iv * gv;
      const float h = ov * tanh_(c);
      h_sh[t] = h;
      out[(size_t)ts * kLH + d * kH + t] = h;
    }
    __syncthreads();
  }
}

// ---------------- pair scorer ----------------
// U:  (kSeq, kMLP) = lstm_out@W1.T, pre-scaled by 2*log2(e)
// VT: (kMLP, kSeq) = (lstm_out@W2.T + b_lin).T, pre-scaled by 2*log2(e)
// score[i][j] = sum_m tanh-of(u+v+b) * w_out[m] + b_out; diag = 0
__global__ __launch_bounds__(512) void score_k(
    const float* __restrict__ Up, const float* __restrict__ VT,
    const float* __restrict__ wout, const float* __restrict__ bout,
    float* __restrict__ out) {
  const int i = blockIdx.x;
  const int j = threadIdx.x;
  __shared__ float u_sh[kMLP];
  __shared__ float w_sh[kMLP];
  u_sh[j] = Up[(size_t)i * kMLP + j];
  w_sh[j] = wout[j];
  __syncthreads();
  float acc = 0.0f;
#pragma unroll 4
  for (int m = 0; m < kMLP; ++m) {
    const float x = u_sh[m] + VT[(size_t)m * kSeq + j];  // already scaled by 2*log2e
    const float th = 1.0f - 2.0f * frcpf(1.0f + fexp2f(x));
    acc = fmaf(th, w_sh[m], acc);
  }
  const float s = acc + bout[0];
  out[(size_t)i * kSeq + j] = (j == i) ? 0.0f : s;
}

extern "C" void kernel_launch(void* const* d_in, const int* in_sizes, int n_in,
                              void* d_out, int out_size, void* d_ws, size_t ws_size,
                              hipStream_t stream) {
  const int*   wt   = (const int*)d_in[0];
  const int*   pt   = (const int*)d_in[1];
  const float* wemb = (const float*)d_in[2];
  const float* pemb = (const float*)d_in[3];
  const float* wih0 = (const float*)d_in[4];
  const float* whh0 = (const float*)d_in[5];
  const float* bih0 = (const float*)d_in[6];
  const float* bhh0 = (const float*)d_in[7];
  const float* wih1 = (const float*)d_in[8];
  const float* whh1 = (const float*)d_in[9];
  const float* bih1 = (const float*)d_in[10];
  const float* bhh1 = (const float*)d_in[11];
  const float* wlin = (const float*)d_in[12];
  const float* blin = (const float*)d_in[13];
  const float* wout = (const float*)d_in[14];
  const float* bout = (const float*)d_in[15];
  float* outp = (float*)d_out;

  float* ws   = (float*)d_ws;
  float* X    = ws;                      // 512*320
  float* PG0  = X + kSeq * kE;           // 2*512*1024
  float* X1   = PG0 + 2 * kSeq * kG;     // 512*512
  float* PG1  = X1 + kSeq * kLH;         // 2*512*1024
  float* LOUT = PG1 + 2 * kSeq * kG;     // 512*512
  float* U    = LOUT + kSeq * kLH;       // 512*512
  float* VT   = U + kSeq * kMLP;         // 512*512

  const float SC = 2.8853900817779268f;  // 2*log2(e), folds tanh scaling

  embed_k<<<kSeq, kE, 0, stream>>>(wt, pt, wemb, pemb, X);

  for (int d = 0; d < 2; ++d) {
    gemm_nt<64, 64, 16><<<dim3(kG / 64, kSeq / 64), 256, 0, stream>>>(
        X, kE, wih0 + (size_t)d * kG * kE, kE,
        bih0 + d * kG, bhh0 + d * kG, 1.0f,
        PG0 + (size_t)d * kSeq * kG, kG, 1, kE);
  }
  lstm_scan<<<2, 1024, 0, stream>>>(PG0, whh0, X1);

  for (int d = 0; d < 2; ++d) {
    gemm_nt<64, 64, 16><<<dim3(kG / 64, kSeq / 64), 256, 0, stream>>>(
        X1, kLH, wih1 + (size_t)d * kG * kLH, kLH,
        bih1 + d * kG, bhh1 + d * kG, 1.0f,
        PG1 + (size_t)d * kSeq * kG, kG, 1, kLH);
  }
  lstm_scan<<<2, 1024, 0, stream>>>(PG1, whh1, LOUT);

  // U = LOUT @ W1.T * SC ; VT = (LOUT @ W2.T + b_lin).T * SC (stored transposed)
  gemm_nt<64, 64, 16><<<dim3(kMLP / 64, kSeq / 64), 256, 0, stream>>>(
      LOUT, kLH, wlin, 2 * kLH, nullptr, nullptr, SC,
      U, kMLP, 1, kLH);
  gemm_nt<64, 64, 16><<<dim3(kMLP / 64, kSeq / 64), 256, 0, stream>>>(
      LOUT, kLH, wlin + kLH, 2 * kLH, blin, nullptr, SC,
      VT, 1, kSeq, kLH);

  score_k<<<kSeq, 512, 0, stream>>>(U, VT, wout, bout, outp);
}

// Round 2
// 2764.018 us; speedup vs baseline: 6.8830x; 6.8830x over previous
//
#include <hip/hip_runtime.h>
#include <cstddef>
#include <cstdint>

constexpr int kSeq = 512;
constexpr int kH   = 256;   // hidden per direction
constexpr int kG   = 1024;  // 4*kH (gates)
constexpr int kE   = 320;   // embed dim
constexpr int kLH  = 512;   // 2*kH
constexpr int kMLP = 512;
constexpr int kSlices = 4;  // blocks per direction
constexpr int kSlice  = kH / kSlices;  // 64 h-elements per block

__device__ __forceinline__ float fexp2f(float x) {
  float r; asm("v_exp_f32 %0, %1" : "=v"(r) : "v"(x)); return r;
}
__device__ __forceinline__ float frcpf(float x) {
  float r; asm("v_rcp_f32 %0, %1" : "=v"(r) : "v"(x)); return r;
}
__device__ __forceinline__ float sigm(float x) {
  return frcpf(1.0f + fexp2f(-1.4426950408889634f * x));
}
__device__ __forceinline__ float tanh_(float x) {
  // tanh(x) = 1 - 2/(1+e^{2x}); e^{2x} = 2^(x*2*log2(e)). inf-safe at both ends.
  return 1.0f - 2.0f * frcpf(1.0f + fexp2f(2.8853900817779268f * x));
}

// ---------------- embedding gather ----------------
__global__ void embed_k(const int* __restrict__ wt, const int* __restrict__ pt,
                        const float* __restrict__ we, const float* __restrict__ pe,
                        float* __restrict__ X) {
  const int t = blockIdx.x;
  const int c = threadIdx.x;  // 0..319
  const int w = wt[t];
  const int p = pt[t];
  X[t * kE + c] = (c < 256) ? we[(size_t)w * 256 + c] : pe[p * 64 + (c - 256)];
}

// ---------------- generic f32 "NT" GEMM ----------------
template <int BM, int BN, int BK>
__global__ __launch_bounds__(256) void gemm_nt(
    const float* __restrict__ A, int lda,
    const float* __restrict__ B, int ldb,
    const float* __restrict__ b1, const float* __restrict__ b2, float scale,
    float* __restrict__ C, int csm, int csn, int K) {
  const int tid = threadIdx.x;
  const int m0 = blockIdx.y * BM;
  const int n0 = blockIdx.x * BN;
  __shared__ float As[BK][BM];
  __shared__ float Bs[BK][BN];
  const int lm = tid >> 2;
  const int lk = tid & 3;
  const int tx = tid & 15;
  const int ty = tid >> 4;
  float acc[4][4] = {};
  for (int k0 = 0; k0 < K; k0 += BK) {
    const float4 av = *(const float4*)(A + (size_t)(m0 + lm) * lda + k0 + lk * 4);
    const float4 bv = *(const float4*)(B + (size_t)(n0 + lm) * ldb + k0 + lk * 4);
    __syncthreads();
    As[lk * 4 + 0][lm] = av.x; As[lk * 4 + 1][lm] = av.y;
    As[lk * 4 + 2][lm] = av.z; As[lk * 4 + 3][lm] = av.w;
    Bs[lk * 4 + 0][lm] = bv.x; Bs[lk * 4 + 1][lm] = bv.y;
    Bs[lk * 4 + 2][lm] = bv.z; Bs[lk * 4 + 3][lm] = bv.w;
    __syncthreads();
#pragma unroll
    for (int kk = 0; kk < BK; ++kk) {
      const float4 a = *(const float4*)&As[kk][ty * 4];
      const float4 b = *(const float4*)&Bs[kk][tx * 4];
      acc[0][0] = fmaf(a.x, b.x, acc[0][0]);
      acc[0][1] = fmaf(a.x, b.y, acc[0][1]);
      acc[0][2] = fmaf(a.x, b.z, acc[0][2]);
      acc[0][3] = fmaf(a.x, b.w, acc[0][3]);
      acc[1][0] = fmaf(a.y, b.x, acc[1][0]);
      acc[1][1] = fmaf(a.y, b.y, acc[1][1]);
      acc[1][2] = fmaf(a.y, b.z, acc[1][2]);
      acc[1][3] = fmaf(a.y, b.w, acc[1][3]);
      acc[2][0] = fmaf(a.z, b.x, acc[2][0]);
      acc[2][1] = fmaf(a.z, b.y, acc[2][1]);
      acc[2][2] = fmaf(a.z, b.z, acc[2][2]);
      acc[2][3] = fmaf(a.z, b.w, acc[2][3]);
      acc[3][0] = fmaf(a.w, b.x, acc[3][0]);
      acc[3][1] = fmaf(a.w, b.y, acc[3][1]);
      acc[3][2] = fmaf(a.w, b.z, acc[3][2]);
      acc[3][3] = fmaf(a.w, b.w, acc[3][3]);
    }
  }
#pragma unroll
  for (int ii = 0; ii < 4; ++ii) {
#pragma unroll
    for (int jj = 0; jj < 4; ++jj) {
      const int m = m0 + ty * 4 + ii;
      const int n = n0 + tx * 4 + jj;
      float v = acc[ii][jj];
      if (b1) v += b1[n];
      if (b2) v += b2[n];
      C[(size_t)m * csm + (size_t)n * csn] = v * scale;
    }
  }
}

// ---------------- persistent multi-block LSTM scan ----------------
// 8 blocks: (dir d = bx>>2, slice s = bx&3). Block owns h elements
// [s*64, s*64+64) of direction d and the 4*64 = 256 gate rows feeding them,
// so cell state c stays block-local. Weights: 64 f32/thread in VGPRs
// (1024 thr = 256 rows x 4 k-quarters; 256KB/CU = half the register file).
// Per step, blocks exchange h slices via global ghbuf (parity double-buffered)
// + per-step agent-scope arrival counters (zeroed each launch by memsetAsync).
__global__ __launch_bounds__(1024, 1) void lstm_scan_mb(
    const float* __restrict__ pre,   // (2, kSeq, kG) pregates
    const float* __restrict__ whh,   // (2, kG, kH)
    float* __restrict__ out,         // (kSeq, kLH); dir d -> cols [d*kH, d*kH+kH)
    float* __restrict__ ghbuf,       // (2 dirs, 2 parity, kH)
    unsigned int* __restrict__ cnt)  // (2 dirs, kSeq), pre-zeroed
{
  const int d = blockIdx.x >> 2;
  const int s = blockIdx.x & 3;
  const int t = threadIdx.x;
  const int q = t >> 8;          // k-quarter (0..3)
  const int r = t & 255;         // local row = g*64 + j
  const int g = r >> 6;          // gate (0..3)
  const int j = r & 63;          // h element within slice
  const int grow = g * kH + s * kSlice + j;  // global gate row

  float4 w4[16];                 // Whh[d][grow][q*64 .. q*64+64) -- 64 VGPRs
  {
    const float4* wp = (const float4*)(whh + ((size_t)d * kG + grow) * kH + q * 64);
#pragma unroll
    for (int k = 0; k < 16; ++k) w4[k] = wp[k];
  }

  __shared__ __align__(16) float h_sh[kH];
  __shared__ float pg[4][256];
  unsigned int* cn = cnt + d * kSeq;
  float* hb = ghbuf + (size_t)d * 2 * kH;
  float c = 0.0f;
  if (t < kH) h_sh[t] = 0.0f;
  __syncthreads();

  for (int u = 0; u < kSeq; ++u) {
    const int ts = d ? (kSeq - 1 - u) : u;
    // pregate prefetch (wave 0 only); latency hides under the dot
    float p0 = 0.f, p1 = 0.f, p2 = 0.f, p3 = 0.f;
    if (t < kSlice) {
      const float* p = pre + ((size_t)d * kSeq + ts) * kG + s * kSlice + j;
      p0 = p[0]; p1 = p[kH]; p2 = p[2 * kH]; p3 = p[3 * kH];
    }
    // partial dot: 64 FMAs over this thread's k-quarter
    const float4* hp = (const float4*)(h_sh + q * 64);
    float a0 = 0.f, a1 = 0.f, a2 = 0.f, a3 = 0.f;
#pragma unroll
    for (int k = 0; k < 16; ++k) {
      const float4 w = w4[k];
      const float4 h = hp[k];
      a0 = fmaf(w.x, h.x, a0);
      a1 = fmaf(w.y, h.y, a1);
      a2 = fmaf(w.z, h.z, a2);
      a3 = fmaf(w.w, h.w, a3);
    }
    pg[q][r] = (a0 + a1) + (a2 + a3);
    __syncthreads();
    if (t < kSlice) {
      const float gi = pg[0][j]       + pg[1][j]       + pg[2][j]       + pg[3][j]       + p0;
      const float gf = pg[0][64 + j]  + pg[1][64 + j]  + pg[2][64 + j]  + pg[3][64 + j]  + p1;
      const float gg = pg[0][128 + j] + pg[1][128 + j] + pg[2][128 + j] + pg[3][128 + j] + p2;
      const float go = pg[0][192 + j] + pg[1][192 + j] + pg[2][192 + j] + pg[3][192 + j] + p3;
      const float iv = sigm(gi), fv = sigm(gf);
      const float gv = tanh_(gg), ov = sigm(go);
      c = fv * c + iv * gv;
      const float h = ov * tanh_(c);
      hb[(u & 1) * kH + s * kSlice + j] = h;
      out[(size_t)ts * kLH + d * kH + s * kSlice + j] = h;
      __threadfence();  // make h stores agent-visible before arrival
      if (t == 0) {
        __hip_atomic_fetch_add(&cn[u], 1u, __ATOMIC_RELEASE, __HIP_MEMORY_SCOPE_AGENT);
        while (__hip_atomic_load(&cn[u], __ATOMIC_ACQUIRE, __HIP_MEMORY_SCOPE_AGENT)
               < (unsigned)kSlices) { }
        __threadfence();  // L1 invalidate before the block reads peers' h
      }
    }
    __syncthreads();
    if (t < 64) {  // reload full h (both parities disjoint; proven race-free)
      ((float4*)h_sh)[t] = ((const float4*)(hb + (u & 1) * kH))[t];
    }
    __syncthreads();
  }
}

// ---------------- pair scorer ----------------
__global__ __launch_bounds__(512) void score_k(
    const float* __restrict__ Up, const float* __restrict__ VT,
    const float* __restrict__ wout, const float* __restrict__ bout,
    float* __restrict__ out) {
  const int i = blockIdx.x;
  const int j = threadIdx.x;
  __shared__ float u_sh[kMLP];
  __shared__ float w_sh[kMLP];
  u_sh[j] = Up[(size_t)i * kMLP + j];
  w_sh[j] = wout[j];
  __syncthreads();
  float acc = 0.0f;
#pragma unroll 4
  for (int m = 0; m < kMLP; ++m) {
    const float x = u_sh[m] + VT[(size_t)m * kSeq + j];  // pre-scaled by 2*log2e
    const float th = 1.0f - 2.0f * frcpf(1.0f + fexp2f(x));
    acc = fmaf(th, w_sh[m], acc);
  }
  const float s = acc + bout[0];
  out[(size_t)i * kSeq + j] = (j == i) ? 0.0f : s;
}

extern "C" void kernel_launch(void* const* d_in, const int* in_sizes, int n_in,
                              void* d_out, int out_size, void* d_ws, size_t ws_size,
                              hipStream_t stream) {
  const int*   wt   = (const int*)d_in[0];
  const int*   pt   = (const int*)d_in[1];
  const float* wemb = (const float*)d_in[2];
  const float* pemb = (const float*)d_in[3];
  const float* wih0 = (const float*)d_in[4];
  const float* whh0 = (const float*)d_in[5];
  const float* bih0 = (const float*)d_in[6];
  const float* bhh0 = (const float*)d_in[7];
  const float* wih1 = (const float*)d_in[8];
  const float* whh1 = (const float*)d_in[9];
  const float* bih1 = (const float*)d_in[10];
  const float* bhh1 = (const float*)d_in[11];
  const float* wlin = (const float*)d_in[12];
  const float* blin = (const float*)d_in[13];
  const float* wout = (const float*)d_in[14];
  const float* bout = (const float*)d_in[15];
  float* outp = (float*)d_out;

  float* ws   = (float*)d_ws;
  float* X    = ws;                      // 512*320
  float* PG0  = X + kSeq * kE;           // 2*512*1024
  float* X1   = PG0 + 2 * kSeq * kG;     // 512*512
  float* PG1  = X1 + kSeq * kLH;         // 2*512*1024
  float* LOUT = PG1 + 2 * kSeq * kG;     // 512*512
  float* U    = LOUT + kSeq * kLH;       // 512*512
  float* VT   = U + kSeq * kMLP;         // 512*512
  float* HB0  = VT + kSeq * kMLP;        // 2*2*256
  float* HB1  = HB0 + 2 * 2 * kH;        // 2*2*256
  unsigned int* CNT0 = (unsigned int*)(HB1 + 2 * 2 * kH);  // 2*512
  unsigned int* CNT1 = CNT0 + 2 * kSeq;                    // 2*512

  const float SC = 2.8853900817779268f;  // 2*log2(e), folds tanh scaling

  hipMemsetAsync(CNT0, 0, 2 * 2 * kSeq * sizeof(unsigned int), stream);

  embed_k<<<kSeq, kE, 0, stream>>>(wt, pt, wemb, pemb, X);

  for (int d = 0; d < 2; ++d) {
    gemm_nt<64, 64, 16><<<dim3(kG / 64, kSeq / 64), 256, 0, stream>>>(
        X, kE, wih0 + (size_t)d * kG * kE, kE,
        bih0 + d * kG, bhh0 + d * kG, 1.0f,
        PG0 + (size_t)d * kSeq * kG, kG, 1, kE);
  }
  lstm_scan_mb<<<2 * kSlices, 1024, 0, stream>>>(PG0, whh0, X1, HB0, CNT0);

  for (int d = 0; d < 2; ++d) {
    gemm_nt<64, 64, 16><<<dim3(kG / 64, kSeq / 64), 256, 0, stream>>>(
        X1, kLH, wih1 + (size_t)d * kG * kLH, kLH,
        bih1 + d * kG, bhh1 + d * kG, 1.0f,
        PG1 + (size_t)d * kSeq * kG, kG, 1, kLH);
  }
  lstm_scan_mb<<<2 * kSlices, 1024, 0, stream>>>(PG1, whh1, LOUT, HB1, CNT1);

  gemm_nt<64, 64, 16><<<dim3(kMLP / 64, kSeq / 64), 256, 0, stream>>>(
      LOUT, kLH, wlin, 2 * kLH, nullptr, nullptr, SC,
      U, kMLP, 1, kLH);
  gemm_nt<64, 64, 16><<<dim3(kMLP / 64, kSeq / 64), 256, 0, stream>>>(
      LOUT, kLH, wlin + kLH, 2 * kLH, blin, nullptr, SC,
      VT, 1, kSeq, kLH);

  score_k<<<kSeq, 512, 0, stream>>>(U, VT, wout, bout, outp);
}

// Round 3
// 2676.465 us; speedup vs baseline: 7.1081x; 1.0327x over previous
//
#include <hip/hip_runtime.h>
#include <cstddef>
#include <cstdint>

constexpr int kSeq = 512;
constexpr int kH   = 256;   // hidden per direction
constexpr int kG   = 1024;  // 4*kH (gates)
constexpr int kE   = 320;   // embed dim
constexpr int kLH  = 512;   // 2*kH
constexpr int kMLP = 512;
constexpr int kSlices = 4;  // blocks per direction
constexpr int kSlice  = kH / kSlices;  // 64 h-elements per block

__device__ __forceinline__ float fexp2f(float x) {
  float r; asm("v_exp_f32 %0, %1" : "=v"(r) : "v"(x)); return r;
}
__device__ __forceinline__ float frcpf(float x) {
  float r; asm("v_rcp_f32 %0, %1" : "=v"(r) : "v"(x)); return r;
}
__device__ __forceinline__ float sigm(float x) {
  return frcpf(1.0f + fexp2f(-1.4426950408889634f * x));
}
__device__ __forceinline__ float tanh_(float x) {
  // tanh(x) = 1 - 2/(1+e^{2x}); e^{2x} = 2^(x*2*log2(e)). inf-safe at both ends.
  return 1.0f - 2.0f * frcpf(1.0f + fexp2f(2.8853900817779268f * x));
}

// ---------------- embedding gather ----------------
__global__ void embed_k(const int* __restrict__ wt, const int* __restrict__ pt,
                        const float* __restrict__ we, const float* __restrict__ pe,
                        float* __restrict__ X) {
  const int t = blockIdx.x;
  const int c = threadIdx.x;  // 0..319
  const int w = wt[t];
  const int p = pt[t];
  X[t * kE + c] = (c < 256) ? we[(size_t)w * 256 + c] : pe[p * 64 + (c - 256)];
}

// ---------------- generic f32 "NT" GEMM ----------------
template <int BM, int BN, int BK>
__global__ __launch_bounds__(256) void gemm_nt(
    const float* __restrict__ A, int lda,
    const float* __restrict__ B, int ldb,
    const float* __restrict__ b1, const float* __restrict__ b2, float scale,
    float* __restrict__ C, int csm, int csn, int K) {
  const int tid = threadIdx.x;
  const int m0 = blockIdx.y * BM;
  const int n0 = blockIdx.x * BN;
  __shared__ float As[BK][BM];
  __shared__ float Bs[BK][BN];
  const int lm = tid >> 2;
  const int lk = tid & 3;
  const int tx = tid & 15;
  const int ty = tid >> 4;
  float acc[4][4] = {};
  for (int k0 = 0; k0 < K; k0 += BK) {
    const float4 av = *(const float4*)(A + (size_t)(m0 + lm) * lda + k0 + lk * 4);
    const float4 bv = *(const float4*)(B + (size_t)(n0 + lm) * ldb + k0 + lk * 4);
    __syncthreads();
    As[lk * 4 + 0][lm] = av.x; As[lk * 4 + 1][lm] = av.y;
    As[lk * 4 + 2][lm] = av.z; As[lk * 4 + 3][lm] = av.w;
    Bs[lk * 4 + 0][lm] = bv.x; Bs[lk * 4 + 1][lm] = bv.y;
    Bs[lk * 4 + 2][lm] = bv.z; Bs[lk * 4 + 3][lm] = bv.w;
    __syncthreads();
#pragma unroll
    for (int kk = 0; kk < BK; ++kk) {
      const float4 a = *(const float4*)&As[kk][ty * 4];
      const float4 b = *(const float4*)&Bs[kk][tx * 4];
      acc[0][0] = fmaf(a.x, b.x, acc[0][0]);
      acc[0][1] = fmaf(a.x, b.y, acc[0][1]);
      acc[0][2] = fmaf(a.x, b.z, acc[0][2]);
      acc[0][3] = fmaf(a.x, b.w, acc[0][3]);
      acc[1][0] = fmaf(a.y, b.x, acc[1][0]);
      acc[1][1] = fmaf(a.y, b.y, acc[1][1]);
      acc[1][2] = fmaf(a.y, b.z, acc[1][2]);
      acc[1][3] = fmaf(a.y, b.w, acc[1][3]);
      acc[2][0] = fmaf(a.z, b.x, acc[2][0]);
      acc[2][1] = fmaf(a.z, b.y, acc[2][1]);
      acc[2][2] = fmaf(a.z, b.z, acc[2][2]);
      acc[2][3] = fmaf(a.z, b.w, acc[2][3]);
      acc[3][0] = fmaf(a.w, b.x, acc[3][0]);
      acc[3][1] = fmaf(a.w, b.y, acc[3][1]);
      acc[3][2] = fmaf(a.w, b.z, acc[3][2]);
      acc[3][3] = fmaf(a.w, b.w, acc[3][3]);
    }
  }
#pragma unroll
  for (int ii = 0; ii < 4; ++ii) {
#pragma unroll
    for (int jj = 0; jj < 4; ++jj) {
      const int m = m0 + ty * 4 + ii;
      const int n = n0 + tx * 4 + jj;
      float v = acc[ii][jj];
      if (b1) v += b1[n];
      if (b2) v += b2[n];
      C[(size_t)m * csm + (size_t)n * csn] = v * scale;
    }
  }
}

// ---------------- persistent multi-block LSTM scan, data-as-flag sync ----------------
// 8 blocks of 256 threads: dir d = bx>>2, slice s = bx&3. Thread t owns ONE full
// gate row grow = g*kH + s*64 + j (g=t>>6, j=t&63): 256 f32 weights in VGPRs
// (launch_bounds(256,1) -> 512-VGPR cap). No LDS reduction needed.
// Cross-block h exchange: comm[d][step][256] pre-zeroed; producers atomic-store
// h+2.0 (never 0 bits) at agent scope; consumers spin on relaxed agent loads of
// exactly the words they need. No counters, no fences, no double buffering:
// each step has a fresh slot, and a block cannot advance without the data.
__global__ __launch_bounds__(256, 1) void lstm_scan_pf(
    const float* __restrict__ pre,   // (2, kSeq, kG) pregates
    const float* __restrict__ whh,   // (2, kG, kH)
    float* __restrict__ out,         // (kSeq, kLH); dir d -> cols [d*kH, d*kH+kH)
    float* __restrict__ comm)        // (2, kSeq, kH), pre-zeroed each launch
{
  const int d = blockIdx.x >> 2;
  const int s = blockIdx.x & 3;
  const int t = threadIdx.x;       // 0..255
  const int g = t >> 6;            // gate 0..3
  const int j = t & 63;            // element within slice
  const int grow = g * kH + s * kSlice + j;

  float4 w[64];                    // full Whh row: 256 f32
  {
    const float4* wp = (const float4*)(whh + ((size_t)d * kG + grow) * kH);
#pragma unroll
    for (int k = 0; k < 64; ++k) w[k] = wp[k];
  }

  __shared__ __align__(16) float h_sh[kH];
  __shared__ float gbuf[256];
  float* cm = comm + (size_t)d * kSeq * kH;
  float c = 0.0f;
  h_sh[t] = 0.0f;
  __syncthreads();

  // poller mapping: threads 64..255 each own one remote word
  const int rid = t - 64;               // 0..191 (valid when t>=64)
  int rsl = rid >> 6;                   // 0..2
  rsl += (rsl >= s) ? 1 : 0;            // skip own slice
  const int rw = (rid & 63);

  for (int u = 0; u < kSeq; ++u) {
    const int ts = d ? (kSeq - 1 - u) : u;
    const float pg = pre[((size_t)d * kSeq + ts) * kG + grow];  // issue early

    // full-row dot: 256 FMAs; h_sh reads are wave-uniform (LDS broadcast)
    const float4* hp = (const float4*)h_sh;
    float a0 = 0.f, a1 = 0.f, a2 = 0.f, a3 = 0.f;
#pragma unroll
    for (int k = 0; k < 64; ++k) {
      const float4 h4 = hp[k];
      const float4 wk = w[k];
      a0 = fmaf(wk.x, h4.x, a0);
      a1 = fmaf(wk.y, h4.y, a1);
      a2 = fmaf(wk.z, h4.z, a2);
      a3 = fmaf(wk.w, h4.w, a3);
    }
    gbuf[t] = (a0 + a1) + (a2 + a3) + pg;
    __syncthreads();

    if (t < kSlice) {
      // update own 64-element slice of c/h
      const float gi = gbuf[t], gf = gbuf[64 + t], gg = gbuf[128 + t], go = gbuf[192 + t];
      const float iv = sigm(gi), fv = sigm(gf);
      const float gv = tanh_(gg), ov = sigm(go);
      c = fv * c + iv * gv;
      const float h = ov * tanh_(c);
      h_sh[s * kSlice + t] = h;
      __hip_atomic_store(&cm[(size_t)u * kH + s * kSlice + t], h + 2.0f,
                         __ATOMIC_RELAXED, __HIP_MEMORY_SCOPE_AGENT);
      out[(size_t)ts * kLH + d * kH + s * kSlice + t] = h;
    } else {
      // poll one remote word; the data IS the flag
      const float* src = &cm[(size_t)u * kH + rsl * kSlice + rw];
      float v;
      do {
        v = __hip_atomic_load(src, __ATOMIC_RELAXED, __HIP_MEMORY_SCOPE_AGENT);
      } while (v == 0.0f);
      h_sh[rsl * kSlice + rw] = v - 2.0f;
    }
    __syncthreads();
  }
}

// ---------------- pair scorer ----------------
__global__ __launch_bounds__(512) void score_k(
    const float* __restrict__ Up, const float* __restrict__ VT,
    const float* __restrict__ wout, const float* __restrict__ bout,
    float* __restrict__ out) {
  const int i = blockIdx.x;
  const int j = threadIdx.x;
  __shared__ float u_sh[kMLP];
  __shared__ float w_sh[kMLP];
  u_sh[j] = Up[(size_t)i * kMLP + j];
  w_sh[j] = wout[j];
  __syncthreads();
  float acc = 0.0f;
#pragma unroll 4
  for (int m = 0; m < kMLP; ++m) {
    const float x = u_sh[m] + VT[(size_t)m * kSeq + j];  // pre-scaled by 2*log2e
    const float th = 1.0f - 2.0f * frcpf(1.0f + fexp2f(x));
    acc = fmaf(th, w_sh[m], acc);
  }
  const float s = acc + bout[0];
  out[(size_t)i * kSeq + j] = (j == i) ? 0.0f : s;
}

extern "C" void kernel_launch(void* const* d_in, const int* in_sizes, int n_in,
                              void* d_out, int out_size, void* d_ws, size_t ws_size,
                              hipStream_t stream) {
  const int*   wt   = (const int*)d_in[0];
  const int*   pt   = (const int*)d_in[1];
  const float* wemb = (const float*)d_in[2];
  const float* pemb = (const float*)d_in[3];
  const float* wih0 = (const float*)d_in[4];
  const float* whh0 = (const float*)d_in[5];
  const float* bih0 = (const float*)d_in[6];
  const float* bhh0 = (const float*)d_in[7];
  const float* wih1 = (const float*)d_in[8];
  const float* whh1 = (const float*)d_in[9];
  const float* bih1 = (const float*)d_in[10];
  const float* bhh1 = (const float*)d_in[11];
  const float* wlin = (const float*)d_in[12];
  const float* blin = (const float*)d_in[13];
  const float* wout = (const float*)d_in[14];
  const float* bout = (const float*)d_in[15];
  float* outp = (float*)d_out;

  float* ws   = (float*)d_ws;
  float* X    = ws;                      // 512*320
  float* PG0  = X + kSeq * kE;           // 2*512*1024
  float* X1   = PG0 + 2 * kSeq * kG;     // 512*512
  float* PG1  = X1 + kSeq * kLH;         // 2*512*1024
  float* LOUT = PG1 + 2 * kSeq * kG;     // 512*512
  float* U    = LOUT + kSeq * kLH;       // 512*512
  float* VT   = U + kSeq * kMLP;         // 512*512
  float* COMM0 = VT + kSeq * kMLP;       // 2*512*256
  float* COMM1 = COMM0 + 2 * kSeq * kH;  // 2*512*256

  const float SC = 2.8853900817779268f;  // 2*log2(e), folds tanh scaling

  // zero both layers' comm buffers (data-as-flag; fresh slot per step)
  hipMemsetAsync(COMM0, 0, 2 * 2 * kSeq * kH * sizeof(float), stream);

  embed_k<<<kSeq, kE, 0, stream>>>(wt, pt, wemb, pemb, X);

  for (int d = 0; d < 2; ++d) {
    gemm_nt<64, 64, 16><<<dim3(kG / 64, kSeq / 64), 256, 0, stream>>>(
        X, kE, wih0 + (size_t)d * kG * kE, kE,
        bih0 + d * kG, bhh0 + d * kG, 1.0f,
        PG0 + (size_t)d * kSeq * kG, kG, 1, kE);
  }
  lstm_scan_pf<<<2 * kSlices, 256, 0, stream>>>(PG0, whh0, X1, COMM0);

  for (int d = 0; d < 2; ++d) {
    gemm_nt<64, 64, 16><<<dim3(kG / 64, kSeq / 64), 256, 0, stream>>>(
        X1, kLH, wih1 + (size_t)d * kG * kLH, kLH,
        bih1 + d * kG, bhh1 + d * kG, 1.0f,
        PG1 + (size_t)d * kSeq * kG, kG, 1, kLH);
  }
  lstm_scan_pf<<<2 * kSlices, 256, 0, stream>>>(PG1, whh1, LOUT, COMM1);

  gemm_nt<64, 64, 16><<<dim3(kMLP / 64, kSeq / 64), 256, 0, stream>>>(
      LOUT, kLH, wlin, 2 * kLH, nullptr, nullptr, SC,
      U, kMLP, 1, kLH);
  gemm_nt<64, 64, 16><<<dim3(kMLP / 64, kSeq / 64), 256, 0, stream>>>(
      LOUT, kLH, wlin + kLH, 2 * kLH, blin, nullptr, SC,
      VT, 1, kSeq, kLH);

  score_k<<<kSeq, 512, 0, stream>>>(U, VT, wout, bout, outp);
}

// Round 4
// 2227.146 us; speedup vs baseline: 8.5422x; 1.2017x over previous
//
#include <hip/hip_runtime.h>
#include <cstddef>
#include <cstdint>

constexpr int kSeq = 512;
constexpr int kH   = 256;   // hidden per direction
constexpr int kG   = 1024;  // 4*kH (gates)
constexpr int kE   = 320;   // embed dim
constexpr int kLH  = 512;   // 2*kH
constexpr int kMLP = 512;
constexpr int kSlices = 4;  // blocks per direction
constexpr int kSlice  = kH / kSlices;  // 64 h-elements per block

__device__ __forceinline__ float fexp2f(float x) {
  float r; asm("v_exp_f32 %0, %1" : "=v"(r) : "v"(x)); return r;
}
__device__ __forceinline__ float frcpf(float x) {
  float r; asm("v_rcp_f32 %0, %1" : "=v"(r) : "v"(x)); return r;
}
__device__ __forceinline__ float sigm(float x) {
  return frcpf(1.0f + fexp2f(-1.4426950408889634f * x));
}
__device__ __forceinline__ float tanh_(float x) {
  // tanh(x) = 1 - 2/(1+e^{2x}); e^{2x} = 2^(x*2*log2(e)). inf-safe at both ends.
  return 1.0f - 2.0f * frcpf(1.0f + fexp2f(2.8853900817779268f * x));
}

// ---------------- embedding gather ----------------
__global__ void embed_k(const int* __restrict__ wt, const int* __restrict__ pt,
                        const float* __restrict__ we, const float* __restrict__ pe,
                        float* __restrict__ X) {
  const int t = blockIdx.x;
  const int c = threadIdx.x;  // 0..319
  const int w = wt[t];
  const int p = pt[t];
  X[t * kE + c] = (c < 256) ? we[(size_t)w * 256 + c] : pe[p * 64 + (c - 256)];
}

// ---------------- generic f32 "NT" GEMM ----------------
template <int BM, int BN, int BK>
__global__ __launch_bounds__(256) void gemm_nt(
    const float* __restrict__ A, int lda,
    const float* __restrict__ B, int ldb,
    const float* __restrict__ b1, const float* __restrict__ b2, float scale,
    float* __restrict__ C, int csm, int csn, int K) {
  const int tid = threadIdx.x;
  const int m0 = blockIdx.y * BM;
  const int n0 = blockIdx.x * BN;
  __shared__ float As[BK][BM];
  __shared__ float Bs[BK][BN];
  const int lm = tid >> 2;
  const int lk = tid & 3;
  const int tx = tid & 15;
  const int ty = tid >> 4;
  float acc[4][4] = {};
  for (int k0 = 0; k0 < K; k0 += BK) {
    const float4 av = *(const float4*)(A + (size_t)(m0 + lm) * lda + k0 + lk * 4);
    const float4 bv = *(const float4*)(B + (size_t)(n0 + lm) * ldb + k0 + lk * 4);
    __syncthreads();
    As[lk * 4 + 0][lm] = av.x; As[lk * 4 + 1][lm] = av.y;
    As[lk * 4 + 2][lm] = av.z; As[lk * 4 + 3][lm] = av.w;
    Bs[lk * 4 + 0][lm] = bv.x; Bs[lk * 4 + 1][lm] = bv.y;
    Bs[lk * 4 + 2][lm] = bv.z; Bs[lk * 4 + 3][lm] = bv.w;
    __syncthreads();
#pragma unroll
    for (int kk = 0; kk < BK; ++kk) {
      const float4 a = *(const float4*)&As[kk][ty * 4];
      const float4 b = *(const float4*)&Bs[kk][tx * 4];
      acc[0][0] = fmaf(a.x, b.x, acc[0][0]);
      acc[0][1] = fmaf(a.x, b.y, acc[0][1]);
      acc[0][2] = fmaf(a.x, b.z, acc[0][2]);
      acc[0][3] = fmaf(a.x, b.w, acc[0][3]);
      acc[1][0] = fmaf(a.y, b.x, acc[1][0]);
      acc[1][1] = fmaf(a.y, b.y, acc[1][1]);
      acc[1][2] = fmaf(a.y, b.z, acc[1][2]);
      acc[1][3] = fmaf(a.y, b.w, acc[1][3]);
      acc[2][0] = fmaf(a.z, b.x, acc[2][0]);
      acc[2][1] = fmaf(a.z, b.y, acc[2][1]);
      acc[2][2] = fmaf(a.z, b.z, acc[2][2]);
      acc[2][3] = fmaf(a.z, b.w, acc[2][3]);
      acc[3][0] = fmaf(a.w, b.x, acc[3][0]);
      acc[3][1] = fmaf(a.w, b.y, acc[3][1]);
      acc[3][2] = fmaf(a.w, b.z, acc[3][2]);
      acc[3][3] = fmaf(a.w, b.w, acc[3][3]);
    }
  }
#pragma unroll
  for (int ii = 0; ii < 4; ++ii) {
#pragma unroll
    for (int jj = 0; jj < 4; ++jj) {
      const int m = m0 + ty * 4 + ii;
      const int n = n0 + tx * 4 + jj;
      float v = acc[ii][jj];
      if (b1) v += b1[n];
      if (b2) v += b2[n];
      C[(size_t)m * csm + (size_t)n * csn] = v * scale;
    }
  }
}

// ---------------- persistent multi-block LSTM scan, latency-overlapped ----------------
// 8 blocks of 256 threads: dir d = bx>>2, slice s = bx&3. Thread t owns one full
// gate row grow = g*kH + s*64 + j. Row dot is split by h-slice:
//   - own-slice partial (64 cols): computed in the PREVIOUS step's poll window
//     (depends only on locally produced h), kept in `pown`.
//   - remote partial (192 cols): computed right after remote h detected.
// Pregates prefetched one step ahead. Sync = data-as-flag (fresh slot per step,
// pre-zeroed comm; producers atomic-store h+2.0 agent-scope; consumers spin).
__global__ __launch_bounds__(256, 1) void lstm_scan_ov(
    const float* __restrict__ pre,   // (2, kSeq, kG) pregates
    const float* __restrict__ whh,   // (2, kG, kH)
    float* __restrict__ out,         // (kSeq, kLH); dir d -> cols [d*kH, d*kH+kH)
    float* __restrict__ comm)        // (2, kSeq, kH), pre-zeroed each launch
{
  const int d = blockIdx.x >> 2;
  const int s = blockIdx.x & 3;
  const int t = threadIdx.x;       // 0..255
  const int g = t >> 6;            // gate 0..3
  const int j = t & 63;            // element within slice
  const int grow = g * kH + s * kSlice + j;

  // weights: own-slice block + 3 remote-slice blocks (row-major float4 view)
  float4 wown[16];
  float4 wrem[3][16];
  {
    const float4* wp = (const float4*)(whh + ((size_t)d * kG + grow) * kH);
#pragma unroll
    for (int k = 0; k < 16; ++k) wown[k] = wp[s * 16 + k];
#pragma unroll
    for (int rr = 0; rr < 3; ++rr) {
      const int ss = rr + (rr >= s ? 1 : 0);
#pragma unroll
      for (int k = 0; k < 16; ++k) wrem[rr][k] = wp[ss * 16 + k];
    }
  }

  __shared__ __align__(16) float h_sh[kH];
  __shared__ float gbuf[256];
  float* cm = comm + (size_t)d * kSeq * kH;
  float c = 0.0f;
  float pown = 0.0f;   // W_own . h_own(u-1); h(-1)=0
  if (t < kH) h_sh[t] = 0.0f;

  // poller mapping: threads 64..255 each own one remote word
  const int rid = t - 64;
  int rsl = rid >> 6;
  rsl += (rsl >= s) ? 1 : 0;
  const int rw = rid & 63;

  // prefetch pregate for u=0
  float pg_cur = pre[((size_t)d * kSeq + (d ? kSeq - 1 : 0)) * kG + grow];
  __syncthreads();

  for (int u = 0; u < kSeq; ++u) {
    const int ts = d ? (kSeq - 1 - u) : u;
    // remote partial over h(u-1) (assembled in h_sh at end of prev iter)
    float a0 = 0.f, a1 = 0.f, a2 = 0.f, a3 = 0.f;
#pragma unroll
    for (int rr = 0; rr < 3; ++rr) {
      const int ss = rr + (rr >= s ? 1 : 0);
      const float4* hp = (const float4*)(h_sh + ss * kSlice);
#pragma unroll
      for (int k = 0; k < 16; ++k) {
        const float4 h4 = hp[k];
        const float4 wk = wrem[rr][k];
        a0 = fmaf(wk.x, h4.x, a0);
        a1 = fmaf(wk.y, h4.y, a1);
        a2 = fmaf(wk.z, h4.z, a2);
        a3 = fmaf(wk.w, h4.w, a3);
      }
    }
    gbuf[t] = (a0 + a1) + (a2 + a3) + pown + pg_cur;
    // prefetch pregate for u+1 (hides HBM latency under gates + poll)
    {
      const int un = (u + 1 < kSeq) ? (u + 1) : u;
      const int tn = d ? (kSeq - 1 - un) : un;
      pg_cur = pre[((size_t)d * kSeq + tn) * kG + grow];
    }
    __syncthreads();

    if (t < kSlice) {
      const float gi = gbuf[t], gf = gbuf[64 + t], gg = gbuf[128 + t], go = gbuf[192 + t];
      const float iv = sigm(gi), fv = sigm(gf);
      const float gv = tanh_(gg), ov = sigm(go);
      c = fv * c + iv * gv;
      const float h = ov * tanh_(c);
      h_sh[s * kSlice + t] = h;
      __hip_atomic_store(&cm[(size_t)u * kH + s * kSlice + t], h + 2.0f,
                         __ATOMIC_RELAXED, __HIP_MEMORY_SCOPE_AGENT);
      out[(size_t)ts * kLH + d * kH + s * kSlice + t] = h;
    }
    __syncthreads();  // h_own(u) visible in h_sh

    if (t >= 64) {
      // poll one remote word of h(u); the data IS the flag
      const float* src = &cm[(size_t)u * kH + rsl * kSlice + rw];
      float v;
      do {
        v = __hip_atomic_load(src, __ATOMIC_RELAXED, __HIP_MEMORY_SCOPE_AGENT);
      } while (v == 0.0f);
      h_sh[rsl * kSlice + rw] = v - 2.0f;
    }
    // own-slice partial for step u+1 (own region of h_sh is stable; disjoint
    // from pollers' writes). Runs inside the poll window for non-pollers,
    // after own poll for pollers (overlaps slower peers).
    {
      const float4* hp = (const float4*)(h_sh + s * kSlice);
      float b0 = 0.f, b1 = 0.f, b2 = 0.f, b3 = 0.f;
#pragma unroll
      for (int k = 0; k < 16; ++k) {
        const float4 h4 = hp[k];
        const float4 wk = wown[k];
        b0 = fmaf(wk.x, h4.x, b0);
        b1 = fmaf(wk.y, h4.y, b1);
        b2 = fmaf(wk.z, h4.z, b2);
        b3 = fmaf(wk.w, h4.w, b3);
      }
      pown = (b0 + b1) + (b2 + b3);
    }
    __syncthreads();  // h(u) fully assembled
  }
}

// ---------------- pair scorer ----------------
__global__ __launch_bounds__(512) void score_k(
    const float* __restrict__ Up, const float* __restrict__ VT,
    const float* __restrict__ wout, const float* __restrict__ bout,
    float* __restrict__ out) {
  const int i = blockIdx.x;
  const int j = threadIdx.x;
  __shared__ float u_sh[kMLP];
  __shared__ float w_sh[kMLP];
  u_sh[j] = Up[(size_t)i * kMLP + j];
  w_sh[j] = wout[j];
  __syncthreads();
  float acc = 0.0f;
#pragma unroll 4
  for (int m = 0; m < kMLP; ++m) {
    const float x = u_sh[m] + VT[(size_t)m * kSeq + j];  // pre-scaled by 2*log2e
    const float th = 1.0f - 2.0f * frcpf(1.0f + fexp2f(x));
    acc = fmaf(th, w_sh[m], acc);
  }
  const float s = acc + bout[0];
  out[(size_t)i * kSeq + j] = (j == i) ? 0.0f : s;
}

extern "C" void kernel_launch(void* const* d_in, const int* in_sizes, int n_in,
                              void* d_out, int out_size, void* d_ws, size_t ws_size,
                              hipStream_t stream) {
  const int*   wt   = (const int*)d_in[0];
  const int*   pt   = (const int*)d_in[1];
  const float* wemb = (const float*)d_in[2];
  const float* pemb = (const float*)d_in[3];
  const float* wih0 = (const float*)d_in[4];
  const float* whh0 = (const float*)d_in[5];
  const float* bih0 = (const float*)d_in[6];
  const float* bhh0 = (const float*)d_in[7];
  const float* wih1 = (const float*)d_in[8];
  const float* whh1 = (const float*)d_in[9];
  const float* bih1 = (const float*)d_in[10];
  const float* bhh1 = (const float*)d_in[11];
  const float* wlin = (const float*)d_in[12];
  const float* blin = (const float*)d_in[13];
  const float* wout = (const float*)d_in[14];
  const float* bout = (const float*)d_in[15];
  float* outp = (float*)d_out;

  float* ws   = (float*)d_ws;
  float* X    = ws;                      // 512*320
  float* PG0  = X + kSeq * kE;           // 2*512*1024
  float* X1   = PG0 + 2 * kSeq * kG;     // 512*512
  float* PG1  = X1 + kSeq * kLH;         // 2*512*1024
  float* LOUT = PG1 + 2 * kSeq * kG;     // 512*512
  float* U    = LOUT + kSeq * kLH;       // 512*512
  float* VT   = U + kSeq * kMLP;         // 512*512
  float* COMM0 = VT + kSeq * kMLP;       // 2*512*256
  float* COMM1 = COMM0 + 2 * kSeq * kH;  // 2*512*256

  const float SC = 2.8853900817779268f;  // 2*log2(e), folds tanh scaling

  // zero both layers' comm buffers (data-as-flag; fresh slot per step)
  hipMemsetAsync(COMM0, 0, 2 * 2 * kSeq * kH * sizeof(float), stream);

  embed_k<<<kSeq, kE, 0, stream>>>(wt, pt, wemb, pemb, X);

  for (int d = 0; d < 2; ++d) {
    gemm_nt<64, 64, 16><<<dim3(kG / 64, kSeq / 64), 256, 0, stream>>>(
        X, kE, wih0 + (size_t)d * kG * kE, kE,
        bih0 + d * kG, bhh0 + d * kG, 1.0f,
        PG0 + (size_t)d * kSeq * kG, kG, 1, kE);
  }
  lstm_scan_ov<<<2 * kSlices, 256, 0, stream>>>(PG0, whh0, X1, COMM0);

  for (int d = 0; d < 2; ++d) {
    gemm_nt<64, 64, 16><<<dim3(kG / 64, kSeq / 64), 256, 0, stream>>>(
        X1, kLH, wih1 + (size_t)d * kG * kLH, kLH,
        bih1 + d * kG, bhh1 + d * kG, 1.0f,
        PG1 + (size_t)d * kSeq * kG, kG, 1, kLH);
  }
  lstm_scan_ov<<<2 * kSlices, 256, 0, stream>>>(PG1, whh1, LOUT, COMM1);

  gemm_nt<64, 64, 16><<<dim3(kMLP / 64, kSeq / 64), 256, 0, stream>>>(
      LOUT, kLH, wlin, 2 * kLH, nullptr, nullptr, SC,
      U, kMLP, 1, kLH);
  gemm_nt<64, 64, 16><<<dim3(kMLP / 64, kSeq / 64), 256, 0, stream>>>(
      LOUT, kLH, wlin + kLH, 2 * kLH, blin, nullptr, SC,
      VT, 1, kSeq, kLH);

  score_k<<<kSeq, 512, 0, stream>>>(U, VT, wout, bout, outp);
}